// Round 1
// baseline (514.001 us; speedup 1.0000x reference)
//
#include <hip/hip_runtime.h>
#include <stdint.h>

#define NROWS 8192
#define NCOLS 8192
#define KTOP  64
#define BLOCK 256
#define QCOLS (NCOLS / 4)   // 2048 float4 per row

// Order-preserving float -> uint32 transform (ascending).
__device__ __forceinline__ uint32_t fkey(float f) {
    uint32_t s = __float_as_uint(f);
    return (s & 0x80000000u) ? ~s : (s | 0x80000000u);
}
__device__ __forceinline__ float finv(uint32_t u) {
    uint32_t s = (u & 0x80000000u) ? (u ^ 0x80000000u) : ~u;
    return __uint_as_float(s);
}

__global__ __launch_bounds__(BLOCK) void topk_mask_kernel(
    const float* __restrict__ x, float* __restrict__ out) {
    // SoA planes: u_lds[j*2048 + c4] holds key of column c4*4 + j
    __shared__ uint32_t u_lds[NCOLS];
    __shared__ uint32_t hist[256];
    __shared__ uint32_t scanbuf[256];
    __shared__ uint32_t eq_idx[256];
    __shared__ uint32_t s_selbin, s_cumabove, s_eqn, s_eqcut;

    const int tid = threadIdx.x;
    const int row = blockIdx.x;
    const float4* __restrict__ xrow = (const float4*)(x + (size_t)row * NCOLS);

    if (tid == 0) s_eqn = 0;

    // ---- Load row, transform to sortable keys, SoA store to LDS ----
    #pragma unroll
    for (int i = 0; i < QCOLS / BLOCK; ++i) {        // 8 iters
        const int c4 = tid + i * BLOCK;
        float4 v = xrow[c4];
        u_lds[0 * 2048 + c4] = fkey(v.x);
        u_lds[1 * 2048 + c4] = fkey(v.y);
        u_lds[2 * 2048 + c4] = fkey(v.z);
        u_lds[3 * 2048 + c4] = fkey(v.w);
    }

    // ---- 4-pass radix select for the KTOP-th largest key ----
    uint32_t pref = 0;     // known high bits of the threshold (aligned in place)
    uint32_t krem = KTOP;  // how many still needed from the current bucket chain

    #pragma unroll
    for (int p = 0; p < 4; ++p) {
        const int shift = 24 - 8 * p;
        // mask of bits already decided (0 for p==0); 64-bit shift avoids UB
        const uint32_t hi_mask = (uint32_t)(0xFFFFFFFFull << (shift + 8));

        hist[tid] = 0;
        __syncthreads();

        #pragma unroll
        for (int i = 0; i < NCOLS / BLOCK; ++i) {    // 32 iters
            uint32_t u = u_lds[tid + i * BLOCK];
            if ((u & hi_mask) == pref)
                atomicAdd(&hist[(u >> shift) & 0xFFu], 1u);
        }
        __syncthreads();

        // reverse copy so a standard inclusive prefix scan gives suffix sums
        scanbuf[tid] = hist[255 - tid];
        __syncthreads();
        for (int off = 1; off < 256; off <<= 1) {
            uint32_t v = scanbuf[tid] + ((tid >= off) ? scanbuf[tid - off] : 0u);
            __syncthreads();
            scanbuf[tid] = v;
            __syncthreads();
        }
        // bin b = tid: S_incl = count of keys in bins >= b (matching prefix)
        {
            uint32_t S_incl = scanbuf[255 - tid];
            uint32_t cnt    = hist[tid];
            uint32_t cumab  = S_incl - cnt;          // strictly above bin tid
            if (cumab < krem && S_incl >= krem) {    // exactly one bin crosses
                s_selbin   = (uint32_t)tid;
                s_cumabove = cumab;
            }
        }
        __syncthreads();
        pref |= (s_selbin << shift);
        krem -= s_cumabove;
        __syncthreads();
    }

    const uint32_t thr = pref;        // exact key of the KTOP-th largest
    // krem = number of elements EQUAL to thr that must be kept (>=1),
    // matching jax.lax.top_k stable tie-break: keep lowest column indices.

    // ---- Collect indices of elements equal to thr ----
    #pragma unroll
    for (int i = 0; i < NCOLS / BLOCK; ++i) {
        const int idx = tid + i * BLOCK;
        if (u_lds[idx] == thr) {
            uint32_t pos = atomicAdd(&s_eqn, 1u);
            const int c4 = idx & 2047;
            const int j  = idx >> 11;
            if (pos < 256u) eq_idx[pos] = (uint32_t)(c4 * 4 + j);
        }
    }
    __syncthreads();
    if (tid == 0) {
        uint32_t m = s_eqn < 256u ? s_eqn : 256u;
        // insertion sort ascending (m is tiny: typically 1)
        for (uint32_t a = 1; a < m; ++a) {
            uint32_t key = eq_idx[a];
            int b = (int)a - 1;
            while (b >= 0 && eq_idx[b] > key) { eq_idx[b + 1] = eq_idx[b]; --b; }
            eq_idx[b + 1] = key;
        }
        uint32_t r = krem;            // equals to keep
        if (r > m) r = m;             // safety clamp (shouldn't trigger)
        s_eqcut = eq_idx[r - 1];      // keep equals with col <= eqcut
    }
    __syncthreads();
    const uint32_t eqcut = s_eqcut;

    // ---- Output pass: keep top-K, zero the rest ----
    float4* __restrict__ orow = (float4*)(out + (size_t)row * NCOLS);
    #pragma unroll
    for (int i = 0; i < QCOLS / BLOCK; ++i) {
        const int c4 = tid + i * BLOCK;
        uint32_t u0 = u_lds[0 * 2048 + c4];
        uint32_t u1 = u_lds[1 * 2048 + c4];
        uint32_t u2 = u_lds[2 * 2048 + c4];
        uint32_t u3 = u_lds[3 * 2048 + c4];
        const uint32_t col = (uint32_t)(c4 * 4);
        float4 o;
        o.x = (u0 > thr || (u0 == thr && (col + 0) <= eqcut)) ? finv(u0) : 0.0f;
        o.y = (u1 > thr || (u1 == thr && (col + 1) <= eqcut)) ? finv(u1) : 0.0f;
        o.z = (u2 > thr || (u2 == thr && (col + 2) <= eqcut)) ? finv(u2) : 0.0f;
        o.w = (u3 > thr || (u3 == thr && (col + 3) <= eqcut)) ? finv(u3) : 0.0f;
        orow[c4] = o;
    }
}

extern "C" void kernel_launch(void* const* d_in, const int* in_sizes, int n_in,
                              void* d_out, int out_size, void* d_ws, size_t ws_size,
                              hipStream_t stream) {
    const float* x = (const float*)d_in[0];
    float* out = (float*)d_out;
    topk_mask_kernel<<<NROWS, BLOCK, 0, stream>>>(x, out);
}